// Round 2
// baseline (1470.374 us; speedup 1.0000x reference)
//
#include <hip/hip_runtime.h>
#include <hip/hip_fp16.h>

// CLDice loss, round 8 (resubmit; round-1 bench was an infra failure, no kernel signal).
// Fuse TWO skeleton iterations per dispatch.
// Identity: with a_k = erode^k(a0):
//   delta_k = relu(a_k - dilate(erode(a_k))), skel += delta_k*(1-skel), in order k=0..10
// Fused pass (pair k,k+1): z-pipeline  a_k -> e1=erode(a_k)=a_{k+1}
//   -> { d1=dilate(e1) -> delta_k,  e2=erode(e1)=a_{k+2} } -> d2=dilate(e2) -> delta_{k+1}
// Both skel updates applied in f32, one skel RMW + one a write per 2 iterations:
// HBM traffic per 2 iters 640->~300 MB, barriers 80->48, dispatches 12+1 -> 6+1.
// Erode/dilate are selections => fp16 lattice stays exact through both fused stages
// (e1 = min of fp16 values is itself an fp16 value). Only skel's store rounds.
// Boundary semantics: each iteration re-pads with +inf (erode) / -inf (dilate).
// e1 is consumed by BOTH: stored with +INF at out-of-volume (erode-neutral);
// the dilate-consumer flips boundary rows/cols to -INF via precomputed masks.
// e2 is dilate-consumed only: stored with -INF outside (mask at write), like round-7's b.
// Last iteration (k=10) uses the round-7 verified single-iteration kernel (MODE 2, reduce).

#define ZD 192
#define YD 192
#define XD 192
constexpr int PLANE = YD * XD;
constexpr int VOL   = ZD * PLANE;
constexpr int NVOL4 = 4 * VOL;

constexpr int XT = 64, YT = 16, ZCH = 16;

// ---- tail (single-iteration, round-7 verified) geometry ----
constexpr int IWQ = 18, SIW = 19;
constexpr int IH  = 20;
constexpr int NIMGQ = IH * IWQ;          // 360
constexpr int BWQ = 17, BH = 18;
constexpr int NBQ  = BH * BWQ;           // 306
constexpr int TSTEPS = ZCH + 4;          // 20

// ---- fused-2 geometry ----
constexpr int AWQ = 18, SAW = 19, AH = 22;   // a: rows y0-3..y0+18, quads x0-4+4c
constexpr int NAQ = AH * AWQ;                // 396
constexpr int EWQ = 17;
constexpr int SE1 = 18, E1H = 20;            // e1: rows y0-2..y0+17, quads x0-2+4c
constexpr int NE1Q = E1H * EWQ;              // 340
constexpr int SE2 = 18, E2H = 18;            // e2: rows y0-1..y0+16, quads x0-1+4c
constexpr int NE2Q = E2H * EWQ;              // 306
constexpr int F2STEPS = ZCH + 8;             // 24; emission at s>=8, zo=z-5

#define PINF __builtin_inff()

__device__ __forceinline__ float4 vf4(float v) { return make_float4(v, v, v, v); }
__device__ __forceinline__ float4 vmin(float4 a, float4 b) {
    return make_float4(fminf(a.x, b.x), fminf(a.y, b.y), fminf(a.z, b.z), fminf(a.w, b.w));
}
__device__ __forceinline__ float4 vmax(float4 a, float4 b) {
    return make_float4(fmaxf(a.x, b.x), fmaxf(a.y, b.y), fmaxf(a.z, b.z), fmaxf(a.w, b.w));
}
__device__ __forceinline__ float4 ldh4(const __half* p) {
    const __half2* q = (const __half2*)p;
    const float2 lo = __half22float2(q[0]);
    const float2 hi = __half22float2(q[1]);
    return make_float4(lo.x, lo.y, hi.x, hi.y);
}
__device__ __forceinline__ void sth4(__half* p, float4 v) {
    __half2* q = (__half2*)p;
    q[0] = __floats2half2_rn(v.x, v.y);
    q[1] = __floats2half2_rn(v.z, v.w);
}

// ============================ fused-2 kernel ============================
// MODE 0: first pair (k=0,1): a0 built inline from logits/targets, skel = delta0 then update.
// MODE 1: mid pair: read a_k + skel, write a_{k+2} + skel.
template <int MODE>
__global__ __launch_bounds__(256, 3)
void fused2_kernel(const __half* __restrict__ a_in,
                   __half* __restrict__ a_out,
                   __half* __restrict__ skel,
                   const float* __restrict__ logits,
                   const int* __restrict__ targets)
{
    __shared__ float sA[AH * SAW * 4];       // 6688 B
    __shared__ float sE1[E1H * SE1 * 4];     // 5760 B
    __shared__ float sE2[E2H * SE2 * 4];     // 5184 B

    const int tx = threadIdx.x, ty = threadIdx.y;   // (16,16)
    const int tid = ty * 16 + tx;
    const int x0 = (blockIdx.x % 3) * XT, y0 = (blockIdx.x / 3) * YT;
    const int z0 = blockIdx.y * ZCH;
    const int zf = blockIdx.z;                      // 0..3
    const int bb = zf & 1, field = zf >> 1;
    const size_t voff = (size_t)zf * VOL;
    const __half* inb  = a_in  + voff;
    __half*       outb = a_out + voff;
    __half*       skb  = skel  + voff;
    const float* lg0 = logits + (size_t)(bb * 2) * VOL;
    const float* lg1 = lg0 + VOL;
    const int*   tgb = targets + (size_t)bb * VOL;

    const int q1off = ((tid & 3) << 6) + (tid >> 2);  // balanced 2nd-chunk id

    // ---- a-plane chunks: qi -> (r=qi/18, c=qi%18), covers (y0-3+r, x0-4+4c)
    int a_ad[2], a_go[2]; bool a_ok[2], a_h[2];
    #pragma unroll
    for (int j = 0; j < 2; ++j) {
        const int qi = (j == 0) ? tid : 256 + q1off;
        const int r = qi / AWQ, c = qi - r * AWQ;
        const int gy = y0 - 3 + r, gxb = x0 - 4 + 4 * c;
        a_h[j]  = (qi < NAQ);
        a_ok[j] = a_h[j] && gy >= 0 && gy < YD && gxb >= 0 && gxb < XD;
        a_go[j] = gy * XD + gxb;
        a_ad[j] = (r * SAW + c) * 4;
    }
    // ---- e1 chunks: store addr in sE1, read addr into sA; +INF outside volume
    int e1st[2], e1rd[2]; bool e1h[2]; float4 e1m[2];
    #pragma unroll
    for (int j = 0; j < 2; ++j) {
        const int qi = (j == 0) ? tid : 256 + q1off;
        const int r = qi / EWQ, c = qi - r * EWQ;
        e1h[j]  = (qi < NE1Q);
        e1st[j] = (r * SE1 + c) * 4;
        e1rd[j] = (r * SAW + c) * 4;
        const int gy = y0 - 2 + r, gxb = x0 - 2 + 4 * c;
        const bool yv = (gy >= 0 && gy < YD);
        float4 m;    // stored e1 = vmax(v, m): valid -> -INF (keep), invalid -> +INF
        m.x = (yv && gxb     >= 0 && gxb     < XD) ? -PINF : PINF;
        m.y = (yv && gxb + 1 >= 0 && gxb + 1 < XD) ? -PINF : PINF;
        m.z = (yv && gxb + 2 >= 0 && gxb + 2 < XD) ? -PINF : PINF;
        m.w = (yv && gxb + 3 >= 0 && gxb + 3 < XD) ? -PINF : PINF;
        e1m[j] = m;
    }
    // ---- e2 chunks: store addr in sE2, read addr into sE1; -INF outside volume
    int e2st[2], e2rd[2]; bool e2h[2]; float4 e2m[2];
    #pragma unroll
    for (int j = 0; j < 2; ++j) {
        const int qi = (j == 0) ? tid : 256 + q1off;
        const int r = qi / EWQ, c = qi - r * EWQ;
        e2h[j]  = (qi < NE2Q);
        e2st[j] = (r * SE2 + c) * 4;
        e2rd[j] = (r * SE1 + c) * 4;
        const int gy = y0 - 1 + r, gxb = x0 - 1 + 4 * c;
        const bool yv = (gy >= 0 && gy < YD);
        float4 m;    // stored e2 = vmin(v, m): valid -> +INF (keep), invalid -> -INF
        m.x = (yv && gxb     >= 0 && gxb     < XD) ? PINF : -PINF;
        m.y = (yv && gxb + 1 >= 0 && gxb + 1 < XD) ? PINF : -PINF;
        m.z = (yv && gxb + 2 >= 0 && gxb + 2 < XD) ? PINF : -PINF;
        m.w = (yv && gxb + 3 >= 0 && gxb + 3 < XD) ? PINF : -PINF;
        e2m[j] = m;
    }

    // ---- output-quad boundary bools (dilate-on-e1 consumer masks)
    const int gy0 = y0 + ty, gx0 = x0 + 4 * tx;
    const bool rok0 = (gy0 > 0), rok2 = (gy0 < YD - 1);
    const bool lok  = (gx0 > 0), rokx = (gx0 + 4 < XD);

    auto loadq = [&](int zi, int j) -> float4 {
        if (zi < 0 || zi >= ZD || zi > z0 + ZCH + 2 || !a_ok[j]) return vf4(PINF);
        const size_t p = (size_t)zi * PLANE + a_go[j];
        if constexpr (MODE == 0) {
            if (field) {
                const int4 t = *(const int4*)(tgb + p);
                return make_float4(t.x == 1 ? 1.f : 0.f, t.y == 1 ? 1.f : 0.f,
                                   t.z == 1 ? 1.f : 0.f, t.w == 1 ? 1.f : 0.f);
            } else {
                const float4 a = *(const float4*)(lg0 + p);
                const float4 b = *(const float4*)(lg1 + p);
                return make_float4(1.f / (1.f + __expf(a.x - b.x)),
                                   1.f / (1.f + __expf(a.y - b.y)),
                                   1.f / (1.f + __expf(a.z - b.z)),
                                   1.f / (1.f + __expf(a.w - b.w)));
            }
        } else {
            return ldh4(inb + p);
        }
    };

    // xy-erode of a-plane at e1-quad position (e1 quad elems: -2+4c..1+4c)
    auto s1_of = [&](int base) -> float4 {
        const float* p = sA + base;
        const float4 A0 = *(const float4*)p;
        const float4 B0 = *(const float4*)(p + 4);
        const float4 A1 = *(const float4*)(p + SAW * 4);
        const float4 B1 = *(const float4*)(p + SAW * 4 + 4);
        const float4 A2 = *(const float4*)(p + SAW * 8);
        const float4 B2 = *(const float4*)(p + SAW * 8 + 4);
        const float4 Ar = vmin(A0, vmin(A1, A2));
        const float4 Br = vmin(B0, vmin(B1, B2));
        const float t1 = fminf(Ar.z, Ar.w);
        const float t2 = fminf(Br.x, Br.y);
        return make_float4(fminf(Ar.y, t1), fminf(t1, Br.x),
                           fminf(Ar.w, t2), fminf(t2, Br.z));
    };
    // xy-erode of e1-plane at e2-quad position (e2 quad elems: -1+4c..2+4c)
    auto s2_of = [&](int base) -> float4 {
        const float* p = sE1 + base;
        const float4 A0 = *(const float4*)p;
        const float4 B0 = *(const float4*)(p + 4);
        const float4 A1 = *(const float4*)(p + SE1 * 4);
        const float4 B1 = *(const float4*)(p + SE1 * 4 + 4);
        const float4 A2 = *(const float4*)(p + SE1 * 8);
        const float4 B2 = *(const float4*)(p + SE1 * 8 + 4);
        const float4 Ar = vmin(A0, vmin(A1, A2));
        const float4 Br = vmin(B0, vmin(B1, B2));
        const float m1 = fminf(Ar.y, Ar.z);
        const float m2 = fminf(Ar.w, Br.x);
        return make_float4(fminf(Ar.x, m1), fminf(m1, Ar.w),
                           fminf(Ar.z, m2), fminf(m2, Br.y));
    };

    // rings
    float4 s1p2a = vf4(PINF), s1p1a = vf4(PINF), s1p2b = vf4(PINF), s1p1b = vf4(PINF);
    float4 s2p2a = vf4(PINF), s2p1a = vf4(PINF), s2p2b = vf4(PINF), s2p1b = vf4(PINF);
    float4 xm1p2 = vf4(-PINF), xm1p1 = vf4(-PINF);
    float4 xm2p2 = vf4(-PINF), xm2p1 = vf4(-PINF);
    float4 e1w0 = vf4(PINF), e1w1 = vf4(PINF), e2w0 = vf4(PINF), e2w1 = vf4(PINF);
    float4 icp1 = vf4(0.f), icp2 = vf4(0.f), icp3 = vf4(0.f);
    float4 ec1 = vf4(0.f), ec2 = vf4(0.f), ec3 = vf4(0.f);
    float4 e2cp = vf4(0.f);
    float4 dl1r1 = vf4(0.f), dl1r2 = vf4(0.f);

    float4 ca0 = loadq(z0 - 3, 0);
    float4 ca1 = loadq(z0 - 3, 1);

    #pragma unroll 1
    for (int s = 0; s < F2STEPS; ++s) {
        const int z = z0 - 3 + s;      // a-plane z stored this step
        // ---------- W phase ----------
        *(float4*)(sA + a_ad[0]) = ca0;
        if (a_h[1]) *(float4*)(sA + a_ad[1]) = ca1;
        if (s >= 1) {                  // e1(z-2), computed last step
            *(float4*)(sE1 + e1st[0]) = vmax(e1w0, e1m[0]);
            if (e1h[1]) *(float4*)(sE1 + e1st[1]) = vmax(e1w1, e1m[1]);
        }
        if (s >= 2) {                  // e2(z-4), computed last step
            *(float4*)(sE2 + e2st[0]) = vmin(e2w0, e2m[0]);
            if (e2h[1]) *(float4*)(sE2 + e2st[1]) = vmin(e2w1, e2m[1]);
        }
        __syncthreads();               // B1: planes ready

        // ---------- C phase ----------
        if (s + 1 < F2STEPS) { ca0 = loadq(z + 1, 0); ca1 = loadq(z + 1, 1); }

        // stage 1: e1 candidate for z-1 (held, stored next step)
        {
            const float4 cur = s1_of(e1rd[0]);
            e1w0 = vmin(s1p2a, vmin(s1p1a, cur));
            s1p2a = s1p1a; s1p1a = cur;
        }
        if (e1h[1]) {
            const float4 cur = s1_of(e1rd[1]);
            e1w1 = vmin(s1p2b, vmin(s1p1b, cur));
            s1p2b = s1p1b; s1p1b = cur;
        }

        const int  ze1 = z - 2;
        const bool ve1 = (s >= 1) && (ze1 >= 0) && (ze1 < ZD);

        // stage 2a: e2 candidate for z-3
        {
            const float4 cur = ve1 ? s2_of(e2rd[0]) : vf4(PINF);
            e2w0 = vmin(s2p2a, vmin(s2p1a, cur));
            s2p2a = s2p1a; s2p1a = cur;
        }
        if (e2h[1]) {
            const float4 cur = ve1 ? s2_of(e2rd[1]) : vf4(PINF);
            e2w1 = vmin(s2p2b, vmin(s2p1b, cur));
            s2p2b = s2p1b; s2p1b = cur;
        }

        // stage 2b: xy-dilate of e1 at output quad (+ e1 center capture)
        float4 xm1c = vf4(-PINF), e1cc = vf4(0.f);
        if (ve1) {
            const float* p = sE1 + ((ty + 1) * SE1 + tx) * 4;
            float4 A0 = *(const float4*)p;
            float4 Bq0 = *(const float4*)(p + 4);
            const float4 A1 = *(const float4*)(p + SE1 * 4);
            const float4 Bq1 = *(const float4*)(p + SE1 * 4 + 4);
            float4 A2 = *(const float4*)(p + SE1 * 8);
            float4 Bq2 = *(const float4*)(p + SE1 * 8 + 4);
            e1cc = make_float4(A1.z, A1.w, Bq1.x, Bq1.y);
            if (!rok0) { A0 = vf4(-PINF); Bq0 = vf4(-PINF); }
            if (!rok2) { A2 = vf4(-PINF); Bq2 = vf4(-PINF); }
            const float4 Ar = vmax(A0, vmax(A1, A2));
            const float4 Br = vmax(Bq0, vmax(Bq1, Bq2));
            const float ay = lok ? Ar.y : -PINF;
            const float bz = rokx ? Br.z : -PINF;
            const float t1 = fmaxf(Ar.z, Ar.w);
            const float t2 = fmaxf(Br.x, Br.y);
            xm1c = make_float4(fmaxf(ay, t1), fmaxf(t1, Br.x),
                               fmaxf(Ar.w, t2), fmaxf(t2, bz));
        }
        const float4 d1v = vmax(xm1p2, vmax(xm1p1, xm1c));   // d1(z-3)
        xm1p2 = xm1p1; xm1p1 = xm1c;

        // stage 3: xy-dilate of e2 at output quad (+ e2 center capture)
        const int  ze2 = z - 4;
        const bool ve2 = (s >= 2) && (ze2 >= 0) && (ze2 < ZD);
        float4 xm2c = vf4(-PINF), e2cc = vf4(0.f);
        if (ve2) {
            const float* p = sE2 + (ty * SE2 + tx) * 4;
            const float4 U0 = *(const float4*)p;
            const float4 V0 = *(const float4*)(p + 4);
            const float4 U1 = *(const float4*)(p + SE2 * 4);
            const float4 V1 = *(const float4*)(p + SE2 * 4 + 4);
            const float4 U2 = *(const float4*)(p + SE2 * 8);
            const float4 V2 = *(const float4*)(p + SE2 * 8 + 4);
            e2cc = make_float4(U1.y, U1.z, U1.w, V1.x);
            const float4 Ur = vmax(U0, vmax(U1, U2));
            const float vx = fmaxf(V0.x, fmaxf(V1.x, V2.x));
            const float vy = fmaxf(V0.y, fmaxf(V1.y, V2.y));
            const float t1 = fmaxf(Ur.y, Ur.z);
            const float t2 = fmaxf(Ur.w, vx);
            xm2c = make_float4(fmaxf(Ur.x, t1), fmaxf(t1, Ur.w),
                               fmaxf(Ur.z, t2), fmaxf(t2, vy));
        }
        const float4 d2v = vmax(xm2p2, vmax(xm2p1, xm2c));   // d2(z-5)
        xm2p2 = xm2p1; xm2p1 = xm2c;

        const float4 icq = *(const float4*)(sA + ((ty + 3) * SAW + tx + 1) * 4);  // a(z) center

        float4 dl1n;   // delta_k(z-3) = relu(a_k(z-3) - d1(z-3))
        dl1n.x = fmaxf(icp3.x - d1v.x, 0.f);
        dl1n.y = fmaxf(icp3.y - d1v.y, 0.f);
        dl1n.z = fmaxf(icp3.z - d1v.z, 0.f);
        dl1n.w = fmaxf(icp3.w - d1v.w, 0.f);
        float4 dl2;    // delta_{k+1}(z-5) = relu(a_{k+1}(z-5) - d2(z-5))
        dl2.x = fmaxf(ec3.x - d2v.x, 0.f);
        dl2.y = fmaxf(ec3.y - d2v.y, 0.f);
        dl2.z = fmaxf(ec3.z - d2v.z, 0.f);
        dl2.w = fmaxf(ec3.w - d2v.w, 0.f);
        const float4 dA = dl1r2;   // delta_k(z-5)
        const float4 av = e2cp;    // a_{k+2}(z-5)

        __syncthreads();           // B2: LDS reads done before next W

        // ---------- emission (registers + global only) ----------
        if (s >= 8) {
            const int zo = z - 5;  // in [z0, z0+15]
            const size_t idx = (size_t)zo * PLANE + (size_t)gy0 * XD + gx0;
            float4 sk;
            if constexpr (MODE == 0) {
                sk = dA;                                   // skel = delta0
            } else {
                const float4 s0 = ldh4(skb + idx);
                sk.x = s0.x + dA.x * (1.f - s0.x);
                sk.y = s0.y + dA.y * (1.f - s0.y);
                sk.z = s0.z + dA.z * (1.f - s0.z);
                sk.w = s0.w + dA.w * (1.f - s0.w);
            }
            float4 sv;
            sv.x = sk.x + dl2.x * (1.f - sk.x);
            sv.y = sk.y + dl2.y * (1.f - sk.y);
            sv.z = sk.z + dl2.z * (1.f - sk.z);
            sv.w = sk.w + dl2.w * (1.f - sk.w);
            sth4(skb + idx, sv);
            sth4(outb + idx, av);
        }

        // ---------- ring shifts ----------
        dl1r2 = dl1r1; dl1r1 = dl1n;
        icp3 = icp2; icp2 = icp1; icp1 = icq;
        ec3 = ec2; ec2 = ec1; ec1 = e1cc;
        e2cp = e2cc;
    }
}

// ============================ tail kernel (round-7 verified; MODE 2 only) ============================
template <int MODE>   // 2=last (k=10; reduce instead of writing)
__global__ __launch_bounds__(256)
void fused_kernel(const __half* __restrict__ a_in,
                  __half* __restrict__ a_out,
                  __half* __restrict__ skel,
                  const float* __restrict__ logits,
                  const int* __restrict__ targets,
                  float* __restrict__ sums)
{
    __shared__ float simg[2][IH * SIW * 4];
    __shared__ float sbp[NBQ * 4 + 8];
    __shared__ float red[4][2];

    const int tx = threadIdx.x, ty = threadIdx.y;   // (16,16)
    const int tid = ty * 16 + tx;
    const int x0 = (blockIdx.x % 3) * XT, y0 = (blockIdx.x / 3) * YT;
    const int z0 = blockIdx.y * ZCH;
    const int zf = blockIdx.z;                      // 0..3
    const int bb = zf & 1, field = zf >> 1;
    const size_t voff = (size_t)zf * VOL;
    const __half* inb  = a_in  + voff;
    __half*       outb = a_out + voff;
    __half*       skb  = skel  + voff;
    const float* lg0 = logits + (size_t)(bb * 2) * VOL;
    const float* lg1 = lg0 + VOL;
    const int*   tgb = targets + (size_t)bb * VOL;

    const int q1off = ((tid & 3) << 6) + (tid >> 2);

    int im_qi[2] = { tid, 256 + q1off };
    int im_addr[2], im_goff[2]; bool im_ok[2], im_has[2];
    #pragma unroll
    for (int j = 0; j < 2; ++j) {
        const int qi = im_qi[j];
        const int r = qi / IWQ, c = qi - r * IWQ;
        const int gy = y0 - 2 + r, gxb = x0 - 4 + 4 * c;
        im_has[j] = (qi < NIMGQ);
        im_ok[j]  = im_has[j] && gy >= 0 && gy < YD && gxb >= 0 && gxb < XD;
        im_goff[j] = gy * XD + gxb;
        im_addr[j] = (r * SIW + c) * 4;
    }
    int bqi[2], brow[2], bcol[2]; bool bhas[2]; float4 bmask[2];
    #pragma unroll
    for (int j = 0; j < 2; ++j) {
        const int qi = (j == 0) ? tid : 256 + q1off;
        bqi[j] = qi;
        bhas[j] = (qi < NBQ);
        const int r = qi / BWQ, c = qi - r * BWQ;
        brow[j] = r; bcol[j] = c;
        const int gy = y0 - 1 + r, gxb = x0 - 1 + 4 * c;
        const bool yv = (gy >= 0 && gy < YD);
        float4 m;
        m.x = (yv && gxb     >= 0 && gxb     < XD) ? PINF : -PINF;
        m.y = (yv && gxb + 1 >= 0 && gxb + 1 < XD) ? PINF : -PINF;
        m.z = (yv && gxb + 2 >= 0 && gxb + 2 < XD) ? PINF : -PINF;
        m.w = (yv && gxb + 3 >= 0 && gxb + 3 < XD) ? PINF : -PINF;
        bmask[j] = m;
    }

    auto loadq = [&](int zi, int j) -> float4 {
        if (zi < 0 || zi >= ZD || !im_ok[j]) return vf4(PINF);
        const size_t p = (size_t)zi * PLANE + im_goff[j];
        return ldh4(inb + p);
    };

    auto s1_of = [&](const float* sp, int j) -> float4 {
        const float* p = sp + brow[j] * (SIW * 4) + 4 * bcol[j];
        const float4 A0 = *(const float4*)p;
        const float4 B0 = *(const float4*)(p + 4);
        const float4 A1 = *(const float4*)(p + SIW * 4);
        const float4 B1 = *(const float4*)(p + SIW * 4 + 4);
        const float4 A2 = *(const float4*)(p + SIW * 8);
        const float4 B2 = *(const float4*)(p + SIW * 8 + 4);
        const float az = fminf(A0.z, fminf(A1.z, A2.z));
        const float aw = fminf(A0.w, fminf(A1.w, A2.w));
        const float4 Br = vmin(B0, vmin(B1, B2));
        const float t1 = fminf(aw, Br.x);
        const float t2 = fminf(Br.y, Br.z);
        return make_float4(fminf(az, t1), fminf(t1, Br.y),
                           fminf(Br.x, t2), fminf(t2, Br.w));
    };

    float4 p2a = vf4(PINF), p1a = vf4(PINF);
    float4 p2b = vf4(PINF), p1b = vf4(PINF);
    float4 s2p1 = vf4(-PINF), s2p2 = vf4(-PINF);
    float4 icp1 = vf4(0.f), icp2 = vf4(0.f), bcp1 = vf4(0.f);
    float sd = 0.f, ss = 0.f;

    float4 ca0 = loadq(z0 - 2, 0);
    float4 ca1 = loadq(z0 - 2, 1);

    #pragma unroll 2
    for (int s = 0; s < TSTEPS; ++s) {
        const int zi = z0 - 2 + s;
        float* sp = simg[s & 1];
        *(float4*)(sp + im_addr[0]) = ca0;
        if (im_has[1]) *(float4*)(sp + im_addr[1]) = ca1;
        if (s + 1 < TSTEPS) { ca0 = loadq(zi + 1, 0); ca1 = loadq(zi + 1, 1); }
        __syncthreads();
        const int zb = zi - 1;
        const bool zbv = (s >= 2) && (zb >= 0) && (zb < ZD);
        {
            const float4 cur = s1_of(sp, 0);
            if (zbv) {
                float4 b = vmin(vmin(p2a, p1a), cur);
                *(float4*)(sbp + 4 * bqi[0]) = vmin(b, bmask[0]);
            }
            p2a = p1a; p1a = cur;
        }
        if (bhas[1]) {
            const float4 cur = s1_of(sp, 1);
            if (zbv) {
                float4 b = vmin(vmin(p2b, p1b), cur);
                *(float4*)(sbp + 4 * bqi[1]) = vmin(b, bmask[1]);
            }
            p2b = p1b; p1b = cur;
        }
        const float4 icq = *(const float4*)(sp + ((ty + 2) * SIW + tx + 1) * 4);
        __syncthreads();
        float4 s2n = vf4(-PINF), bcq = vf4(0.f);
        if (zbv) {
            const float* p = sbp + (ty * BWQ + tx) * 4;
            const float4 U0 = *(const float4*)p;
            const float4 V0 = *(const float4*)(p + 4);
            const float4 U1 = *(const float4*)(p + BWQ * 4);
            const float4 V1 = *(const float4*)(p + BWQ * 4 + 4);
            const float4 U2 = *(const float4*)(p + BWQ * 8);
            const float4 V2 = *(const float4*)(p + BWQ * 8 + 4);
            bcq = make_float4(U1.y, U1.z, U1.w, V1.x);
            const float4 Ur = vmax(U0, vmax(U1, U2));
            const float vx = fmaxf(V0.x, fmaxf(V1.x, V2.x));
            const float vy = fmaxf(V0.y, fmaxf(V1.y, V2.y));
            const float t1 = fmaxf(Ur.y, Ur.z);
            const float t2 = fmaxf(Ur.w, vx);
            s2n.x = fmaxf(Ur.x, t1);
            s2n.y = fmaxf(t1, Ur.w);
            s2n.z = fmaxf(Ur.z, t2);
            s2n.w = fmaxf(t2, vy);
        }
        if (s >= 4) {
            const int zo = zi - 2;
            const float4 d = vmax(s2p2, vmax(s2p1, s2n));
            float4 dl;
            dl.x = fmaxf(icp2.x - d.x, 0.f);
            dl.y = fmaxf(icp2.y - d.y, 0.f);
            dl.z = fmaxf(icp2.z - d.z, 0.f);
            dl.w = fmaxf(icp2.w - d.w, 0.f);
            const size_t idx = (size_t)zo * PLANE + (size_t)(y0 + ty) * XD + (x0 + 4 * tx);
            const float4 sk = ldh4(skb + idx);
            float4 sv;
            sv.x = sk.x + dl.x * (1.f - sk.x);
            sv.y = sk.y + dl.y * (1.f - sk.y);
            sv.z = sk.z + dl.z * (1.f - sk.z);
            sv.w = sk.w + dl.w * (1.f - sk.w);
            float4 w;
            if (field) {
                const float4 a = *(const float4*)(lg0 + idx);
                const float4 b = *(const float4*)(lg1 + idx);
                w = make_float4(1.f / (1.f + __expf(a.x - b.x)),
                                1.f / (1.f + __expf(a.y - b.y)),
                                1.f / (1.f + __expf(a.z - b.z)),
                                1.f / (1.f + __expf(a.w - b.w)));
            } else {
                const int4 t = *(const int4*)(tgb + idx);
                w = make_float4(t.x == 1 ? 1.f : 0.f, t.y == 1 ? 1.f : 0.f,
                                t.z == 1 ? 1.f : 0.f, t.w == 1 ? 1.f : 0.f);
            }
            sd += sv.x * w.x + sv.y * w.y + sv.z * w.z + sv.w * w.w;
            ss += sv.x + sv.y + sv.z + sv.w;
        }
        s2p2 = s2p1; s2p1 = s2n;
        icp2 = icp1; icp1 = icq;
        bcp1 = bcq;
        (void)bcp1; (void)outb;
    }

    if constexpr (MODE == 2) {
        #pragma unroll
        for (int o = 32; o; o >>= 1) {
            sd += __shfl_down(sd, o, 64);
            ss += __shfl_down(ss, o, 64);
        }
        const int w = tid >> 6;
        if ((tid & 63) == 0) { red[w][0] = sd; red[w][1] = ss; }
        __syncthreads();
        if (tid == 0) {
            float a = 0.f, b = 0.f;
            #pragma unroll
            for (int i = 0; i < 4; ++i) { a += red[i][0]; b += red[i][1]; }
            atomicAdd(&sums[2 * field + 0], a);
            atomicAdd(&sums[2 * field + 1], b);
        }
    }
}

__global__ void final_kernel(const float* __restrict__ sums, float* __restrict__ out)
{
    float tprec = (sums[0] + 1.f) / (sums[1] + 1.f);
    float tsens = (sums[2] + 1.f) / (sums[3] + 1.f);
    float cl = 2.f * tprec * tsens / (tprec + tsens + 1e-7f);
    out[0] = 1.f - cl;
}

extern "C" void kernel_launch(void* const* d_in, const int* in_sizes, int n_in,
                              void* d_out, int out_size, void* d_ws, size_t ws_size,
                              hipStream_t stream)
{
    const float* logits  = (const float*)d_in[0];
    const int*   targets = (const int*)d_in[1];
    float* out  = (float*)d_out;

    float*  sums = (float*)d_ws;
    __half* A    = (__half*)(sums + 16);
    __half* B    = A + NVOL4;
    __half* SK   = B + NVOL4;

    hipMemsetAsync(sums, 0, 16 * sizeof(float), stream);

    dim3 g(3 * (YD / YT), ZD / ZCH, 4);    // (36, 12, 4) = 1728 blocks
    dim3 blk(16, 16, 1);

    // pairs (0,1),(2,3),(4,5),(6,7),(8,9): 5 fused dispatches
    fused2_kernel<0><<<g, blk, 0, stream>>>(A, A, SK, logits, targets);  // a2 -> A
    fused2_kernel<1><<<g, blk, 0, stream>>>(A, B, SK, logits, targets);  // a4 -> B
    fused2_kernel<1><<<g, blk, 0, stream>>>(B, A, SK, logits, targets);  // a6 -> A
    fused2_kernel<1><<<g, blk, 0, stream>>>(A, B, SK, logits, targets);  // a8 -> B
    fused2_kernel<1><<<g, blk, 0, stream>>>(B, A, SK, logits, targets);  // a10 -> A
    // k = 10: read a10 (in A), update skel in-reg, weighted reduce
    fused_kernel<2><<<g, blk, 0, stream>>>(A, B, SK, logits, targets, sums);

    final_kernel<<<1, 1, 0, stream>>>(sums, out);
}

// Round 4
// 981.725 us; speedup vs baseline: 1.4977x; 1.4977x over previous
//
#include <hip/hip_runtime.h>
#include <hip/hip_fp16.h>

// CLDice loss, round 9b: round-7 verified structure + PACKED fp16 LDS planes.
// Round-8 post-mortem: fusing 2 iterations scaled time by exactly 2x => the
// binding pipe is LDS (reads + conflicts), not HBM or dispatch count.
// This round halves+ LDS bytes (b64/b32 instead of b128) and halves min/max
// VALU via v_pk_min_f16 / v_pk_max_f16 (__builtin_elementwise_min/max on
// _Float16 ext-vectors; ROCm 7.2 lacks __hmin2/__hmax2 -- round-9 compile fix).
// Element shifts across pack boundaries via v_alignbit_b32.
// Erode/dilate are selections and min/max commutes with monotone rounding =>
// all eroded/dilated state is bit-identical to round-7; only delta0 sees a0
// pre-rounded to fp16 (<=2.4e-4, unbiased; final scalar err ~1e-3 << 1e-2).
// Structure: MODE 0 (k=0, a0 inline from logits/targets, skel=delta0),
// MODE 1 x9 (a_k -> a_{k+1}, skel update), MODE 2 (k=10, weighted reduce).

#define ZD 192
#define YD 192
#define XD 192
constexpr int PLANE = YD * XD;
constexpr int VOL   = ZD * PLANE;        // one (batch) volume
constexpr int NVOL4 = 4 * VOL;           // 2 fields x 2 batches

constexpr int XT = 64, YT = 16, ZCH = 16;
constexpr int IWQ = 18, SIW = 19;        // img real quads / padded LDS stride (quads)
constexpr int IH  = 20;                  // rows y0-2..y0+17
constexpr int NIMGQ = IH * IWQ;          // 360
constexpr int BWQ = 17, BH = 18;         // b plane: origin x0-1, rows y0-1..y0+16
constexpr int NBQ  = BH * BWQ;           // 306
constexpr int STEPS = ZCH + 4;           // 20
#define PINF __builtin_inff()

typedef _Float16 hv2 __attribute__((ext_vector_type(2)));
// 4 halfs = 8 B = one "quad"
struct __align__(8) H4 { hv2 lo, hi; };

__device__ __forceinline__ unsigned h2u(hv2 h) { return __builtin_bit_cast(unsigned, h); }
__device__ __forceinline__ hv2 u2h(unsigned u) { return __builtin_bit_cast(hv2, u); }

__device__ __forceinline__ hv2 h2min(hv2 a, hv2 b) {
#if __has_builtin(__builtin_elementwise_min)
    return __builtin_elementwise_min(a, b);
#else
    unsigned r, ua = h2u(a), ub = h2u(b);
    asm("v_pk_min_f16 %0, %1, %2" : "=v"(r) : "v"(ua), "v"(ub));
    return u2h(r);
#endif
}
__device__ __forceinline__ hv2 h2max(hv2 a, hv2 b) {
#if __has_builtin(__builtin_elementwise_max)
    return __builtin_elementwise_max(a, b);
#else
    unsigned r, ua = h2u(a), ub = h2u(b);
    asm("v_pk_max_f16 %0, %1, %2" : "=v"(r) : "v"(ua), "v"(ub));
    return u2h(r);
#endif
}
// {c.y, n.x}: one-element left shift across a packed pair boundary
__device__ __forceinline__ hv2 shf1(hv2 c, hv2 n) {
    return u2h(__builtin_amdgcn_alignbit(h2u(n), h2u(c), 16));
}
__device__ __forceinline__ H4 h4min(H4 a, H4 b) { H4 r; r.lo = h2min(a.lo, b.lo); r.hi = h2min(a.hi, b.hi); return r; }
__device__ __forceinline__ H4 h4max(H4 a, H4 b) { H4 r; r.lo = h2max(a.lo, b.lo); r.hi = h2max(a.hi, b.hi); return r; }
__device__ __forceinline__ H4 pk4(float4 v) {
    H4 r;
    r.lo.x = (_Float16)v.x; r.lo.y = (_Float16)v.y;
    r.hi.x = (_Float16)v.z; r.hi.y = (_Float16)v.w;
    return r;
}
__device__ __forceinline__ H4 ldp4(const __half* p) {
    const uint2 v = *(const uint2*)p;
    H4 r; r.lo = u2h(v.x); r.hi = u2h(v.y); return r;
}
__device__ __forceinline__ void stp4(__half* p, H4 v) {
    uint2 u; u.x = h2u(v.lo); u.y = h2u(v.hi);
    *(uint2*)p = u;
}
__device__ __forceinline__ void sth4(__half* p, float4 v) { stp4(p, pk4(v)); }

template <int MODE>   // 0=k0, 1=mid, 2=last
__global__ __launch_bounds__(256)
void fused_kernel(const __half* __restrict__ a_in,
                  __half* __restrict__ a_out,
                  __half* __restrict__ skel,
                  const float* __restrict__ logits,
                  const int* __restrict__ targets,
                  float* __restrict__ sums)
{
    __shared__ __align__(16) hv2 simg[2][IH * SIW * 2];   // 2 x 3040 B
    __shared__ __align__(16) hv2 sbp[NBQ * 2 + 4];        // 2464 B
    __shared__ float red[4][2];

    const int tx = threadIdx.x, ty = threadIdx.y;   // (16,16)
    const int tid = ty * 16 + tx;
    const int x0 = (blockIdx.x % 3) * XT, y0 = (blockIdx.x / 3) * YT;
    const int z0 = blockIdx.y * ZCH;
    const int zf = blockIdx.z;                      // 0..3
    const int bb = zf & 1, field = zf >> 1;
    const size_t voff = (size_t)zf * VOL;
    const __half* inb  = a_in  + voff;
    __half*       outb = a_out + voff;
    __half*       skb  = skel  + voff;
    const float* lg0 = logits + (size_t)(bb * 2) * VOL;
    const float* lg1 = lg0 + VOL;
    const int*   tgb = targets + (size_t)bb * VOL;

    const hv2 INF2  = u2h(0x7C007C00u);
    const hv2 NINF2 = u2h(0xFC00FC00u);
    const hv2 Z2    = u2h(0u);
    const H4 HINF4  = { INF2, INF2 };
    const H4 HNINF4 = { NINF2, NINF2 };
    const H4 HZ4    = { Z2, Z2 };

    const int q1off = ((tid & 3) << 6) + (tid >> 2);  // balanced 2nd-chunk id

    // ---- img chunks: qi -> row r=qi/18, col c=qi%18; LDS addr (r*SIW+c)*2 (hv2 units)
    int im_qi[2] = { tid, 256 + q1off };
    int im_addr[2], im_goff[2]; bool im_ok[2], im_has[2];
    #pragma unroll
    for (int j = 0; j < 2; ++j) {
        const int qi = im_qi[j];
        const int r = qi / IWQ, c = qi - r * IWQ;
        const int gy = y0 - 2 + r, gxb = x0 - 4 + 4 * c;
        im_has[j] = (qi < NIMGQ);
        im_ok[j]  = im_has[j] && gy >= 0 && gy < YD && gxb >= 0 && gxb < XD;
        im_goff[j] = gy * XD + gxb;
        im_addr[j] = (r * SIW + c) * 2;
    }
    // ---- b chunks: qi -> (r=qi/17, c=qi%17); covers (y0-1+r, x0-1+4c)
    int bqi[2], brow[2], bcol[2]; bool bhas[2]; H4 bmask[2];
    #pragma unroll
    for (int j = 0; j < 2; ++j) {
        const int qi = (j == 0) ? tid : 256 + q1off;
        bqi[j] = qi;
        bhas[j] = (qi < NBQ);
        const int r = qi / BWQ, c = qi - r * BWQ;
        brow[j] = r; bcol[j] = c;
        const int gy = y0 - 1 + r, gxb = x0 - 1 + 4 * c;
        const bool yv = (gy >= 0 && gy < YD);
        float4 m;
        m.x = (yv && gxb     >= 0 && gxb     < XD) ? PINF : -PINF;
        m.y = (yv && gxb + 1 >= 0 && gxb + 1 < XD) ? PINF : -PINF;
        m.z = (yv && gxb + 2 >= 0 && gxb + 2 < XD) ? PINF : -PINF;
        m.w = (yv && gxb + 3 >= 0 && gxb + 3 < XD) ? PINF : -PINF;
        bmask[j] = pk4(m);
    }

    auto loadq = [&](int zi, int j) -> H4 {
        if (zi < 0 || zi >= ZD || !im_ok[j]) return HINF4;
        const size_t p = (size_t)zi * PLANE + im_goff[j];
        if constexpr (MODE == 0) {
            if (field) {
                const int4 t = *(const int4*)(tgb + p);
                return pk4(make_float4(t.x == 1 ? 1.f : 0.f, t.y == 1 ? 1.f : 0.f,
                                       t.z == 1 ? 1.f : 0.f, t.w == 1 ? 1.f : 0.f));
            } else {
                const float4 a = *(const float4*)(lg0 + p);
                const float4 b = *(const float4*)(lg1 + p);
                return pk4(make_float4(1.f / (1.f + __expf(a.x - b.x)),
                                       1.f / (1.f + __expf(a.y - b.y)),
                                       1.f / (1.f + __expf(a.z - b.z)),
                                       1.f / (1.f + __expf(a.w - b.w))));
            }
        } else {
            return ldp4(inb + p);
        }
    };

    // erode xy-min for b slot j from img plane sp; elements s=[a2,a3,b0..b3],
    // out_i = min(s_i, s_{i+1}, s_{i+2})
    auto s1_of = [&](const hv2* sp, int j) -> H4 {
        const hv2* p = sp + (brow[j] * SIW + bcol[j]) * 2;
        const hv2 A0 = p[1];                            // {a2,a3} row 0 (b32)
        const hv2 A1 = p[SIW * 2 + 1];
        const hv2 A2 = p[SIW * 4 + 1];
        const H4 B0 = *(const H4*)(p + 2);              // {b0..b3} (b64)
        const H4 B1 = *(const H4*)(p + SIW * 2 + 2);
        const H4 B2 = *(const H4*)(p + SIW * 4 + 2);
        const hv2 Ah = h2min(A0, h2min(A1, A2));        // {a2,a3}
        const hv2 Bl = h2min(B0.lo, h2min(B1.lo, B2.lo));   // {b0,b1}
        const hv2 Bh = h2min(B0.hi, h2min(B1.hi, B2.hi));   // {b2,b3}
        const hv2 S1 = shf1(Ah, Bl);   // {a3,b0}
        const hv2 S2 = shf1(Bl, Bh);   // {b1,b2}
        H4 r;
        r.lo = h2min(Ah, h2min(S1, Bl));   // {min(a2,a3,b0), min(a3,b0,b1)}
        r.hi = h2min(Bl, h2min(S2, Bh));   // {min(b0,b1,b2), min(b1,b2,b3)}
        return r;
    };

    H4 p2a = HINF4, p1a = HINF4;   // s1 z-ring chunk0
    H4 p2b = HINF4, p1b = HINF4;   // s1 z-ring chunk1
    H4 s2p1 = HNINF4, s2p2 = HNINF4;
    H4 icp1 = HZ4, icp2 = HZ4, bcp1 = HZ4;
    float sd = 0.f, ss = 0.f;

    H4 ca0 = loadq(z0 - 2, 0);
    H4 ca1 = loadq(z0 - 2, 1);

    #pragma unroll 2
    for (int s = 0; s < STEPS; ++s) {
        const int zi = z0 - 2 + s;
        hv2* sp = simg[s & 1];
        *(H4*)&sp[im_addr[0]] = ca0;
        if (im_has[1]) *(H4*)&sp[im_addr[1]] = ca1;
        if (s + 1 < STEPS) { ca0 = loadq(zi + 1, 0); ca1 = loadq(zi + 1, 1); }
        __syncthreads();                        // B1: simg[s&1] ready
        const int zb = zi - 1;
        const bool zbv = (s >= 2) && (zb >= 0) && (zb < ZD);
        {
            const H4 cur = s1_of(sp, 0);
            if (zbv) {
                const H4 b = h4min(h4min(p2a, p1a), cur);
                *(H4*)&sbp[2 * bqi[0]] = h4min(b, bmask[0]);
            }
            p2a = p1a; p1a = cur;
        }
        if (bhas[1]) {
            const H4 cur = s1_of(sp, 1);
            if (zbv) {
                const H4 b = h4min(h4min(p2b, p1b), cur);
                *(H4*)&sbp[2 * bqi[1]] = h4min(b, bmask[1]);
            }
            p2b = p1b; p1b = cur;
        }
        const H4 icq = *(const H4*)&sp[((ty + 2) * SIW + tx + 1) * 2];
        __syncthreads();                        // B2: b plane ready
        // dilate xy-max at output quad (tx,ty) from b rows ty..ty+2, quads tx (full) + V.lo
        H4 s2n = HNINF4, bcq = HZ4;
        if (zbv) {
            const hv2* p = sbp + (ty * BWQ + tx) * 2;
            const H4 U0 = *(const H4*)p;                    // b64
            const H4 U1 = *(const H4*)(p + BWQ * 2);
            const H4 U2 = *(const H4*)(p + BWQ * 4);
            const hv2 V0 = p[2];                            // {v0,v1} (b32)
            const hv2 V1 = p[BWQ * 2 + 2];
            const hv2 V2 = p[BWQ * 4 + 2];
            bcq.lo = shf1(U1.lo, U1.hi);       // {u1,u2}
            bcq.hi = shf1(U1.hi, V1);          // {u3,v0}
            const hv2 Ul = h2max(U0.lo, h2max(U1.lo, U2.lo));   // {m0,m1}
            const hv2 Uh = h2max(U0.hi, h2max(U1.hi, U2.hi));   // {m2,m3}
            const hv2 Vl = h2max(V0, h2max(V1, V2));            // {mv0,mv1}
            const hv2 S1 = shf1(Ul, Uh);   // {m1,m2}
            const hv2 S2 = shf1(Uh, Vl);   // {m3,mv0}
            s2n.lo = h2max(Ul, h2max(S1, Uh));   // {max(m0..m2), max(m1..m3)}
            s2n.hi = h2max(Uh, h2max(S2, Vl));   // {max(m2,m3,mv0), max(m3,mv0,mv1)}
        }
        // emit zo = zi-2
        if (s >= 4) {
            const int zo = zi - 2;
            const H4 d = h4max(s2p2, h4max(s2p1, s2n));
            float4 dl;
            dl.x = fmaxf((float)icp2.lo.x - (float)d.lo.x, 0.f);
            dl.y = fmaxf((float)icp2.lo.y - (float)d.lo.y, 0.f);
            dl.z = fmaxf((float)icp2.hi.x - (float)d.hi.x, 0.f);
            dl.w = fmaxf((float)icp2.hi.y - (float)d.hi.y, 0.f);
            const size_t idx = (size_t)zo * PLANE + (size_t)(y0 + ty) * XD + (x0 + 4 * tx);
            if constexpr (MODE == 0) {
                sth4(skb + idx, dl);              // skel = delta0
                stp4(outb + idx, bcp1);           // a1 (already fp16-packed)
            } else {
                const H4 sk = ldp4(skb + idx);
                const float s0x = (float)sk.lo.x, s0y = (float)sk.lo.y;
                const float s0z = (float)sk.hi.x, s0w = (float)sk.hi.y;
                float4 sv;
                sv.x = s0x + dl.x * (1.f - s0x);
                sv.y = s0y + dl.y * (1.f - s0y);
                sv.z = s0z + dl.z * (1.f - s0z);
                sv.w = s0w + dl.w * (1.f - s0w);
                if constexpr (MODE == 1) {
                    sth4(skb + idx, sv);
                    stp4(outb + idx, bcp1);       // a_{k+1}
                } else {
                    float4 w;
                    if (field) {                  // gt skeleton weighted by pred
                        const float4 a = *(const float4*)(lg0 + idx);
                        const float4 b = *(const float4*)(lg1 + idx);
                        w = make_float4(1.f / (1.f + __expf(a.x - b.x)),
                                        1.f / (1.f + __expf(a.y - b.y)),
                                        1.f / (1.f + __expf(a.z - b.z)),
                                        1.f / (1.f + __expf(a.w - b.w)));
                    } else {                      // pred skeleton weighted by gt
                        const int4 t = *(const int4*)(tgb + idx);
                        w = make_float4(t.x == 1 ? 1.f : 0.f, t.y == 1 ? 1.f : 0.f,
                                        t.z == 1 ? 1.f : 0.f, t.w == 1 ? 1.f : 0.f);
                    }
                    sd += sv.x * w.x + sv.y * w.y + sv.z * w.z + sv.w * w.w;
                    ss += sv.x + sv.y + sv.z + sv.w;
                }
            }
        }
        s2p2 = s2p1; s2p1 = s2n;
        icp2 = icp1; icp1 = icq;
        bcp1 = bcq;
    }

    if constexpr (MODE == 2) {
        #pragma unroll
        for (int o = 32; o; o >>= 1) {
            sd += __shfl_down(sd, o, 64);
            ss += __shfl_down(ss, o, 64);
        }
        const int w = tid >> 6;
        if ((tid & 63) == 0) { red[w][0] = sd; red[w][1] = ss; }
        __syncthreads();
        if (tid == 0) {
            float a = 0.f, b = 0.f;
            #pragma unroll
            for (int i = 0; i < 4; ++i) { a += red[i][0]; b += red[i][1]; }
            atomicAdd(&sums[2 * field + 0], a);
            atomicAdd(&sums[2 * field + 1], b);
        }
    }
}

__global__ void final_kernel(const float* __restrict__ sums, float* __restrict__ out)
{
    float tprec = (sums[0] + 1.f) / (sums[1] + 1.f);
    float tsens = (sums[2] + 1.f) / (sums[3] + 1.f);
    float cl = 2.f * tprec * tsens / (tprec + tsens + 1e-7f);
    out[0] = 1.f - cl;
}

extern "C" void kernel_launch(void* const* d_in, const int* in_sizes, int n_in,
                              void* d_out, int out_size, void* d_ws, size_t ws_size,
                              hipStream_t stream)
{
    const float* logits  = (const float*)d_in[0];
    const int*   targets = (const int*)d_in[1];
    float* out  = (float*)d_out;

    float*  sums = (float*)d_ws;
    __half* A    = (__half*)(sums + 16);
    __half* B    = A + NVOL4;
    __half* SK   = B + NVOL4;
    __half* bufs[2] = { A, B };

    hipMemsetAsync(sums, 0, 16 * sizeof(float), stream);

    dim3 g(3 * (YD / YT), ZD / ZCH, 4);    // (36, 12, 4) = 1728 blocks
    dim3 blk(16, 16, 1);

    // k = 0: build a0 inline, skel = delta0, write a1 -> A
    fused_kernel<0><<<g, blk, 0, stream>>>(A, A, SK, logits, targets, sums);
    // k = 1..9: a_k -> a_{k+1}, update skel
    for (int k = 1; k <= 9; ++k) {
        const __half* cin = bufs[(k + 1) & 1];
        __half*       cout = bufs[k & 1];
        fused_kernel<1><<<g, blk, 0, stream>>>(cin, cout, SK, logits, targets, sums);
    }
    // k = 10: read a10 (in B), reduce
    fused_kernel<2><<<g, blk, 0, stream>>>(bufs[1], A, SK, logits, targets, sums);

    final_kernel<<<1, 1, 0, stream>>>(sums, out);
}